// Round 1
// baseline (121.480 us; speedup 1.0000x reference)
//
#include <hip/hip_runtime.h>
#include <math.h>

#define TEMP_F 0.07f
#define NCON 20
#define LDIM 512
#define NROWS 32768
#define NSEL 16384

// ws layout:
// float [0..511]      ebar_sz
// float [512..1023]   ebar_nsz
// u32   [1024]        keep-mask sz  (bit j set => concept j kept)
// u32   [1025]        keep-mask nsz
// u32   [2048 .. 2048+NROWS)  packed counts: low16 = #times row in sz_idx,
//                                            high16 = #times row in nsz_idx

__global__ __launch_bounds__(256) void prep_kernel(const float* __restrict__ all_emb,
                                                   const int* __restrict__ Psz,
                                                   const int* __restrict__ Pnsz,
                                                   float* __restrict__ ws,
                                                   float* __restrict__ out) {
    unsigned* cnt = (unsigned*)ws + 2048;
    const int b = blockIdx.x;
    if (b < 128) {                       // 128*256 = 32768: zero the count table
        cnt[b * 256 + threadIdx.x] = 0u;
        return;
    }
    // block 128: concept means + keep masks + out zero (256 threads, 2 cols each)
    const int l = threadIdx.x;
    float s1 = 0.f, s2 = 0.f, n1 = 0.f, n2 = 0.f;
#pragma unroll
    for (int k = 0; k < 5; ++k) {
        s1 += all_emb[Psz[k]  * LDIM + l];
        s2 += all_emb[Psz[k]  * LDIM + l + 256];
        n1 += all_emb[Pnsz[k] * LDIM + l];
        n2 += all_emb[Pnsz[k] * LDIM + l + 256];
    }
    ws[l]             = s1 * 0.2f;   // mean over 5 (duplicates counted, matches ref)
    ws[l + 256]       = s2 * 0.2f;
    ws[512 + l]       = n1 * 0.2f;
    ws[512 + l + 256] = n2 * 0.2f;
    if (l == 0) {
        unsigned m = (1u << NCON) - 1u, m2 = (1u << NCON) - 1u;
#pragma unroll
        for (int k = 0; k < 5; ++k) { m &= ~(1u << Psz[k]); m2 &= ~(1u << Pnsz[k]); }
        ((unsigned*)ws)[1024] = m;
        ((unsigned*)ws)[1025] = m2;
        out[0] = 0.f;                // d_out is poisoned before every launch
    }
}

// 128 blocks x 256 = 32768 threads: one packed atomic increment per selection
__global__ __launch_bounds__(256) void hist_kernel(const int* __restrict__ sz_idx,
                                                   const int* __restrict__ nsz_idx,
                                                   float* __restrict__ ws) {
    unsigned* cnt = (unsigned*)ws + 2048;
    const int t = blockIdx.x * 256 + threadIdx.x;
    if (t < NSEL) atomicAdd(&cnt[sz_idx[t]], 1u);            // low 16 bits
    else          atomicAdd(&cnt[nsz_idx[t - NSEL]], 65536u); // high 16 bits
}

__device__ inline float dot4(float4 a, float4 b) {
    return a.x * b.x + a.y * b.y + a.z * b.z + a.w * b.w;
}

// One streaming pass: wave per row, 8 consecutive rows per wave, skip count==0 rows.
// 1024 blocks x 256 threads = 4096 waves x 8 rows = 32768 rows.
__global__ __launch_bounds__(256) void fused_kernel(const float* __restrict__ hg,
                                                    const float* __restrict__ sim,
                                                    const float* __restrict__ ws,
                                                    float* __restrict__ out) {
    const float4* hg4     = (const float4*)hg;
    const float4* eb_sz4  = (const float4*)ws;            // 128 float4
    const float4* eb_nsz4 = (const float4*)(ws + 512);
    const unsigned* cnt   = (const unsigned*)ws + 2048;
    const unsigned msz    = ((const unsigned*)ws)[1024];
    const unsigned mnsz   = ((const unsigned*)ws)[1025];

    const int wave = threadIdx.x >> 6;
    const int lane = threadIdx.x & 63;

    const float4 es0 = eb_sz4[lane * 2];
    const float4 es1 = eb_sz4[lane * 2 + 1];
    const float4 en0 = eb_nsz4[lane * 2];
    const float4 en1 = eb_nsz4[lane * 2 + 1];

    const float invT = 1.0f / TEMP_F;
    float acc = 0.f;
    const int row0 = blockIdx.x * 32 + wave * 8;

#pragma unroll
    for (int it = 0; it < 8; ++it) {
        const int r = row0 + it;
        const unsigned c = cnt[r];          // wave-uniform load
        if (c == 0u) continue;              // row never selected: skip its 2 KB

        const float4* rp = hg4 + (size_t)r * (LDIM / 4) + lane * 2;
        const float4 a0 = rp[0];
        const float4 a1 = rp[1];

        float ss = dot4(a0, a0) + dot4(a1, a1);
        float ds = dot4(a0, es0) + dot4(a1, es1);
        float dn = dot4(a0, en0) + dot4(a1, en1);

        // denominators: lanes 0..19 hold one concept each (coalesced 80B row read)
        float e_s = 0.f, e_n = 0.f;
        if (lane < NCON) {
            const float ex = expf(sim[(size_t)r * NCON + lane] * invT);
            if (msz  & (1u << lane)) e_s = ex;
            if (mnsz & (1u << lane)) e_n = ex;
        }

#pragma unroll
        for (int off = 32; off; off >>= 1) {
            ss += __shfl_xor(ss, off);
            ds += __shfl_xor(ds, off);
            dn += __shfl_xor(dn, off);
        }
#pragma unroll
        for (int off = 16; off; off >>= 1) {  // lanes 0..31 suffice (20..31 are 0)
            e_s += __shfl_xor(e_s, off);
            e_n += __shfl_xor(e_n, off);
        }

        // lane 0 now holds full sums; other lanes' acc is discarded below
        const float rn  = invT / fmaxf(sqrtf(ss), 1e-12f);
        const float csz = (float)(c & 0xffffu);
        const float cns = (float)(c >> 16);
        acc += csz * (logf(e_s) - ds * rn) + cns * (logf(e_n) - dn * rn);
    }

    __shared__ float red[4];
    if (lane == 0) red[wave] = acc;
    __syncthreads();
    if (threadIdx.x == 0)
        atomicAdd(out, (red[0] + red[1] + red[2] + red[3]) * (1.0f / NSEL));
}

extern "C" void kernel_launch(void* const* d_in, const int* in_sizes, int n_in,
                              void* d_out, int out_size, void* d_ws, size_t ws_size,
                              hipStream_t stream) {
    const float* hg      = (const float*)d_in[0];
    const float* hg_corr = (const float*)d_in[1];
    const float* all_emb = (const float*)d_in[2];
    const int*   sz_idx  = (const int*)d_in[3];
    const int*   nsz_idx = (const int*)d_in[4];
    const int*   Psz     = (const int*)d_in[5];
    const int*   Pnsz    = (const int*)d_in[6];
    float* out = (float*)d_out;
    float* ws  = (float*)d_ws;

    prep_kernel<<<129, 256, 0, stream>>>(all_emb, Psz, Pnsz, ws, out);
    hist_kernel<<<128, 256, 0, stream>>>(sz_idx, nsz_idx, ws);
    fused_kernel<<<1024, 256, 0, stream>>>(hg, hg_corr, ws, out);
}